// Round 3
// baseline (174.047 us; speedup 1.0000x reference)
//
#include <hip/hip_runtime.h>

// y = (x + pe) * keep / 0.9
// pe[s,d] = sin(s / 10000^(2d/D)) if d even else cos(...)
// B=8, S=4096, D=512 -> 16,777,216 fp32 elements. Memory-bound.
//
// v3: persistent grid (2048 blocks = 8/CU, no workgroup churn). Each thread owns
//     one (s,d) site and loops over the batch dim (stride S*D), so the 4 PE
//     transcendentals are computed ONCE per thread (was 8x), and the 8 load-pairs
//     are independent so the compiler can keep many in flight per wave.

static constexpr float KEEP_SCALE = 1.0f / 0.9f;          // 1/(1-p)
static constexpr float INV_2PI    = 0.15915494309189535f; // 1/(2*pi)
// 10000^(-2/512)
static constexpr float RATIO      = 0.96466155f;
// -(2/512) * log2(10000)
static constexpr float C_LOG2     = -0.05190512648261547f;

typedef float nfloat4 __attribute__((ext_vector_type(4))); // native vec for builtins

__device__ __forceinline__ float sin_rev(float a) {
    float r = a * INV_2PI;
    r -= floorf(r);                       // range-reduce to [0,1) revolutions
    return __builtin_amdgcn_sinf(r);      // v_sin_f32: input in revolutions
}
__device__ __forceinline__ float cos_rev(float a) {
    float r = a * INV_2PI;
    r -= floorf(r);
    return __builtin_amdgcn_cosf(r);      // v_cos_f32: input in revolutions
}

__device__ __forceinline__ void store_nt(float4* p, float4 v) {
    nfloat4 nv;
    nv.x = v.x; nv.y = v.y; nv.z = v.z; nv.w = v.w;
    __builtin_nontemporal_store(nv, reinterpret_cast<nfloat4*>(p));
}

// ---------------- fast path: exact bench shape B=8, S=4096, D=512 ----------------
#define SLICE4 (4096 * 512 / 4)   // float4s per batch slice = 524288
#define NBATCH 8

__global__ __launch_bounds__(256) void pe_dropout_fast(
    const float4* __restrict__ x,
    const float4* __restrict__ m,
    float4* __restrict__ o)
{
    int idx = blockIdx.x * 256 + threadIdx.x;   // [0, 524288): one (s,d) site
    int e   = idx << 2;
    int d   = e & 511;                // D = 512
    float s = (float)(e >> 9);        // row within slice, < 4096

    // PE computed once, reused across all 8 batches (same s,d each step)
    float inv0 = exp2f(C_LOG2 * (float)d);
    float inv1 = inv0 * RATIO;
    float inv2 = inv1 * RATIO;
    float inv3 = inv2 * RATIO;
    float pe0 = sin_rev(s * inv0);
    float pe1 = cos_rev(s * inv1);
    float pe2 = sin_rev(s * inv2);
    float pe3 = cos_rev(s * inv3);

    #pragma unroll
    for (int b = 0; b < NBATCH; ++b) {
        int i = idx + b * SLICE4;
        float4 xv = x[i];
        float4 mv = m[i];
        float4 yv;
        yv.x = (xv.x + pe0) * (mv.x >= 0.1f ? KEEP_SCALE : 0.0f);
        yv.y = (xv.y + pe1) * (mv.y >= 0.1f ? KEEP_SCALE : 0.0f);
        yv.z = (xv.z + pe2) * (mv.z >= 0.1f ? KEEP_SCALE : 0.0f);
        yv.w = (xv.w + pe3) * (mv.w >= 0.1f ? KEEP_SCALE : 0.0f);
        store_nt(&o[i], yv);          // streaming store: output never re-read
    }
}

// ---------------- generic fallback (any shape, D=512/S=4096 layout) ----------------
__global__ __launch_bounds__(256) void pe_dropout_generic(
    const float4* __restrict__ x,
    const float4* __restrict__ m,
    float4* __restrict__ o,
    int total4)
{
    int idx = blockIdx.x * 256 + threadIdx.x;
    if (idx >= total4) return;

    int e = idx << 2;
    int d = e & 511;
    float s = (float)((e >> 9) & 4095);

    float inv0 = exp2f(C_LOG2 * (float)d);
    float inv1 = inv0 * RATIO;
    float inv2 = inv1 * RATIO;
    float inv3 = inv2 * RATIO;

    float4 xv = x[idx];
    float4 mv = m[idx];
    float4 yv;
    yv.x = (xv.x + sin_rev(s * inv0)) * (mv.x >= 0.1f ? KEEP_SCALE : 0.0f);
    yv.y = (xv.y + cos_rev(s * inv1)) * (mv.y >= 0.1f ? KEEP_SCALE : 0.0f);
    yv.z = (xv.z + sin_rev(s * inv2)) * (mv.z >= 0.1f ? KEEP_SCALE : 0.0f);
    yv.w = (xv.w + cos_rev(s * inv3)) * (mv.w >= 0.1f ? KEEP_SCALE : 0.0f);
    store_nt(&o[idx], yv);
}

extern "C" void kernel_launch(void* const* d_in, const int* in_sizes, int n_in,
                              void* d_out, int out_size, void* d_ws, size_t ws_size,
                              hipStream_t stream) {
    const float* x = (const float*)d_in[0];
    const float* m = (const float*)d_in[1];
    float* out = (float*)d_out;

    int n = in_sizes[0];              // 16,777,216 for the bench shape

    if (n == NBATCH * SLICE4 * 4) {
        // 524288 threads / 256 = 2048 blocks = 8 per CU (persistent, one round)
        pe_dropout_fast<<<2048, 256, 0, stream>>>(
            (const float4*)x, (const float4*)m, (float4*)out);
    } else {
        int total4 = n >> 2;
        int blocks = (total4 + 255) / 256;
        pe_dropout_generic<<<blocks, 256, 0, stream>>>(
            (const float4*)x, (const float4*)m, (float4*)out, total4);
    }
}

// Round 4
// 156.779 us; speedup vs baseline: 1.1101x; 1.1101x over previous
//
#include <hip/hip_runtime.h>

// y = (x + pe) * keep / 0.9
// pe[s,d] = sin(s / 10000^(2d/D)) if d even else cos(...)
// B=8, S=4096, D=512 -> 16,777,216 fp32 elements. Memory-bound.
//
// v4: v2 structure (one-shot grid, 4x block-interleaved unroll, PE chain hoisted)
//     + NON-TEMPORAL LOADS as well as stores. FETCH_SIZE == output size exactly
//     (deterministic) => suspected store write-allocate/RFO traffic + L2 read-churn
//     forcing mid-dispatch writebacks. nt on both sides: reads don't allocate
//     (MALL hits still served; inputs stay resident), stores stream without RFO.

static constexpr float KEEP_SCALE = 1.0f / 0.9f;          // 1/(1-p)
static constexpr float INV_2PI    = 0.15915494309189535f; // 1/(2*pi)
// 10000^(-2/512)
static constexpr float RATIO      = 0.96466155f;
// -(2/512) * log2(10000)
static constexpr float C_LOG2     = -0.05190512648261547f;

typedef float nfloat4 __attribute__((ext_vector_type(4))); // native vec for builtins

__device__ __forceinline__ float sin_rev(float a) {
    float r = a * INV_2PI;
    r -= floorf(r);                       // range-reduce to [0,1) revolutions
    return __builtin_amdgcn_sinf(r);      // v_sin_f32: input in revolutions
}
__device__ __forceinline__ float cos_rev(float a) {
    float r = a * INV_2PI;
    r -= floorf(r);
    return __builtin_amdgcn_cosf(r);      // v_cos_f32: input in revolutions
}

__device__ __forceinline__ nfloat4 load_nt(const float4* p) {
    return __builtin_nontemporal_load(reinterpret_cast<const nfloat4*>(p));
}
__device__ __forceinline__ void store_nt(float4* p, nfloat4 v) {
    __builtin_nontemporal_store(v, reinterpret_cast<nfloat4*>(p));
}

#define UNROLL 4

__global__ __launch_bounds__(256) void pe_dropout_kernel(
    const float4* __restrict__ x,
    const float4* __restrict__ m,
    float4* __restrict__ o,
    int total4)
{
    int base = blockIdx.x * (256 * UNROLL) + threadIdx.x;

    // Unroll stride = 256 float4 = 1024 elements = 2 full rows of D=512,
    // so d is IDENTICAL across the unroll and s advances by 2 per step.
    int e  = base << 2;
    int d  = e & 511;                 // D = 512
    int s0 = (e >> 9) & 4095;         // S = 4096

    if (base + (UNROLL - 1) * 256 < total4) {
        // ---- fast path: issue all 8 loads (nt) before any compute ----
        nfloat4 xv[UNROLL], mv[UNROLL];
        #pragma unroll
        for (int k = 0; k < UNROLL; ++k) {
            xv[k] = load_nt(&x[base + k * 256]);
            mv[k] = load_nt(&m[base + k * 256]);
        }

        // inv_i = 10000^(-2*(d+i)/512); computed ONCE (d constant across unroll)
        float inv0 = exp2f(C_LOG2 * (float)d);
        float inv1 = inv0 * RATIO;
        float inv2 = inv1 * RATIO;
        float inv3 = inv2 * RATIO;

        #pragma unroll
        for (int k = 0; k < UNROLL; ++k) {
            float s = (float)((s0 + 2 * k) & 4095);
            nfloat4 yv;
            yv.x = (xv[k].x + sin_rev(s * inv0)) * (mv[k].x >= 0.1f ? KEEP_SCALE : 0.0f);
            yv.y = (xv[k].y + cos_rev(s * inv1)) * (mv[k].y >= 0.1f ? KEEP_SCALE : 0.0f);
            yv.z = (xv[k].z + sin_rev(s * inv2)) * (mv[k].z >= 0.1f ? KEEP_SCALE : 0.0f);
            yv.w = (xv[k].w + cos_rev(s * inv3)) * (mv[k].w >= 0.1f ? KEEP_SCALE : 0.0f);
            store_nt(&o[base + k * 256], yv);
        }
    } else {
        // ---- tail path (not hit for the bench shape, kept for generality) ----
        float inv0 = exp2f(C_LOG2 * (float)d);
        float inv1 = inv0 * RATIO;
        float inv2 = inv1 * RATIO;
        float inv3 = inv2 * RATIO;

        for (int k = 0; k < UNROLL; ++k) {
            int idx = base + k * 256;
            if (idx >= total4) break;
            float s = (float)((s0 + 2 * k) & 4095);
            nfloat4 xv = load_nt(&x[idx]);
            nfloat4 mv = load_nt(&m[idx]);
            nfloat4 yv;
            yv.x = (xv.x + sin_rev(s * inv0)) * (mv.x >= 0.1f ? KEEP_SCALE : 0.0f);
            yv.y = (xv.y + cos_rev(s * inv1)) * (mv.y >= 0.1f ? KEEP_SCALE : 0.0f);
            yv.z = (xv.z + sin_rev(s * inv2)) * (mv.z >= 0.1f ? KEEP_SCALE : 0.0f);
            yv.w = (xv.w + cos_rev(s * inv3)) * (mv.w >= 0.1f ? KEEP_SCALE : 0.0f);
            store_nt(&o[idx], yv);
        }
    }
}

extern "C" void kernel_launch(void* const* d_in, const int* in_sizes, int n_in,
                              void* d_out, int out_size, void* d_ws, size_t ws_size,
                              hipStream_t stream) {
    const float* x = (const float*)d_in[0];
    const float* m = (const float*)d_in[1];
    float* out = (float*)d_out;

    int n = in_sizes[0];                      // 16,777,216 (divisible by 1024)
    int total4 = n >> 2;                      // 4,194,304 float4's
    int per_block = 256 * UNROLL;             // 1024 float4's per block
    int blocks = (total4 + per_block - 1) / per_block;   // 4096

    pe_dropout_kernel<<<blocks, 256, 0, stream>>>(
        (const float4*)x, (const float4*)m, (float4*)out, total4);
}